// Round 2
// baseline (511.160 us; speedup 1.0000x reference)
//
#include <hip/hip_runtime.h>

#define T 256
#define SC 32            // super-chunk: 32 steps staged per round
#define NSC (T / SC)     // 8 super-chunks
#define V 64             // one vehicle per thread, SINGLE-WAVE blocks
#define DT 0.05f
#define WHEELBASE 2.7f
#define MAX_STEER 0.5235987755982988f  // deg2rad(30)
#define MAX_SPEED 100.0f
#define FR 0.1f
#define FA 0.01f

#define CTL_ROW_F4 9     // 8 float4 payload + 1 float4 pad per control row
#define ST_PITCH  33     // 32 + 1 pad floats per state row

// Wave-local LDS fence: orders ds_write -> ds_read across lanes of ONE wave.
// No s_barrier, no vmcnt wait: global stores stay in flight and drain under
// the next phase's compute; DS unit processes a wave's LDS ops in order.
__device__ __forceinline__ void lds_fence() {
    asm volatile("s_waitcnt lgkmcnt(0)" ::: "memory");
}

// One thread per vehicle, one wave per block (grid=1024 -> 4 blocks/CU).
//
// Per super-chunk (32 steps):
//  1. ds_write the prefetched control tile [64 veh][32 t] (loaded COALESCED:
//     8 consecutive lanes read one vehicle-row's 128 B = full lines, 8 full
//     lines per instruction -> 1 L1 request per line instead of 64 scattered
//     16 B requests per instruction).
//  2. fence; each thread ds_read_b128's its own row back (pad 9 float4/row
//     -> conflict-free per 8-lane phase: start bank 4*(tid+k) mod 32).
//  3. issue coalesced prefetch of next tile into registers (vmcnt naturally
//     waited right before next iteration's ds_write -> hidden under sim).
//  4. simulate 32 steps, staging pre-step state into LDS (aliases the dead
//     control tile; single wave + in-order DS unit = no race).
//  5. fence; transposed writeout: 32 consecutive lanes write one vehicle's
//     32 floats = 128 B full line, nontemporal.
__global__ __launch_bounds__(V) void bicycle_kernel(
    const float* __restrict__ sx, const float* __restrict__ sy,
    const float* __restrict__ syaw, const float* __restrict__ ssp,
    const float* __restrict__ accel, const float* __restrict__ steering,
    float* __restrict__ out, int B)
{
    // 4 planes * 64 veh * 33 floats = 8448 floats = 33,792 B -> 4 blocks/CU.
    // Control tile view: [2 arrays][64 rows][9 float4] = 1152 float4 = 18,432 B
    // (aliases the front of the pool; dead before state staging overwrites it).
    __shared__ float pool[4 * V * ST_PITCH];
    float4* ctlA = (float4*)pool;                 // accel rows
    float4* ctlS = ctlA + V * CTL_ROW_F4;         // steering rows

    const int tid = threadIdx.x;
    const int b   = blockIdx.x * V + tid;

    float x   = sx[b];
    float y   = sy[b];
    float yaw = syaw[b];
    float sp  = ssp[b];

    const float4* gA = (const float4*)accel;
    const float4* gS = (const float4*)steering;

    const size_t plane   = (size_t)B * T;
    const size_t vehBase = (size_t)blockIdx.x * V;

    // coalesced-load lane mapping: inst i covers rows i*8..i*8+7, each row's
    // 8 float4s (128 B) read by 8 consecutive lanes.
    const int lrow = tid >> 3;    // 0..7 within the 8-row group
    const int lcol = tid & 7;     // float4 column 0..7

    // writeout lane mapping: 32 consecutive lanes write one vehicle row.
    const int wu = tid >> 5;      // 0..1: which vehicle of the pair
    const int wj = tid & 31;      // time offset within super-chunk

    // ---- prologue: prefetch super-chunk 0's control tile (coalesced)
    float4 avn[SC / 4], svn[SC / 4];
    #pragma unroll
    for (int i = 0; i < SC / 4; ++i) {
        const size_t r = vehBase + i * 8 + lrow;
        avn[i] = gA[r * (T / 4) + lcol];
        svn[i] = gS[r * (T / 4) + lcol];
    }

    for (int c = 0; c < NSC; ++c) {
        // ---- 1. stage control tile to LDS (conflict-free per 8-lane phase)
        #pragma unroll
        for (int i = 0; i < SC / 4; ++i) {
            const int r = i * 8 + lrow;
            ctlA[r * CTL_ROW_F4 + lcol] = avn[i];
            ctlS[r * CTL_ROW_F4 + lcol] = svn[i];
        }
        lds_fence();

        // ---- 2. read back own row (b128, conflict-free), unpack to scalars
        float4 af4[SC / 4], sf4[SC / 4];
        #pragma unroll
        for (int k = 0; k < SC / 4; ++k) {
            af4[k] = ctlA[tid * CTL_ROW_F4 + k];
            sf4[k] = ctlS[tid * CTL_ROW_F4 + k];
        }
        float ac[SC], scn[SC];
        #pragma unroll
        for (int k = 0; k < SC / 4; ++k) {
            ac[4*k+0]  = af4[k].x; ac[4*k+1]  = af4[k].y; ac[4*k+2]  = af4[k].z; ac[4*k+3]  = af4[k].w;
            scn[4*k+0] = sf4[k].x; scn[4*k+1] = sf4[k].y; scn[4*k+2] = sf4[k].z; scn[4*k+3] = sf4[k].w;
        }

        // ---- 3. prefetch next super-chunk's tile (drains under sim+writeout)
        if (c + 1 < NSC) {
            #pragma unroll
            for (int i = 0; i < SC / 4; ++i) {
                const size_t r = vehBase + i * 8 + lrow;
                avn[i] = gA[r * (T / 4) + (c + 1) * (SC / 4) + lcol];
                svn[i] = gS[r * (T / 4) + (c + 1) * (SC / 4) + lcol];
            }
        }

        // ---- 4. simulate 32 steps, record pre-step state into LDS
        // sim write banks: (33*tid + t) % 32 = (tid+t)%32 -> 2-way, free.
        #pragma unroll
        for (int t = 0; t < SC; ++t) {
            pool[(0 * V + tid) * ST_PITCH + t] = x;
            pool[(1 * V + tid) * ST_PITCH + t] = y;
            pool[(2 * V + tid) * ST_PITCH + t] = yaw;
            pool[(3 * V + tid) * ST_PITCH + t] = sp;

            float fr    = fmaf(FA * sp, sp, sp * FR);
            float spn   = fmaf(DT, ac[t] - fr, sp);
            spn         = fminf(fmaxf(spn, 0.0f), MAX_SPEED);
            float steer = fminf(fmaxf(scn[t], -MAX_STEER), MAX_STEER);
            float angv  = sp * __tanf(steer) * (1.0f / WHEELBASE);
            float s_, c_;
            __sincosf(yaw, &s_, &c_);
            float spDT = sp * DT;
            x   = fmaf(spDT, c_, x);
            y   = fmaf(spDT, s_, y);
            yaw = fmaf(angv, DT, yaw);
            sp  = spn;
        }
        lds_fence();

        // ---- 5. transposed writeout: lanes (wu,wj) -> vehicle i*2+wu, time wj.
        // 32 consecutive lanes = 128 B contiguous, aligned (c*32*4 = 128 B
        // multiple) -> full L2 lines, written exactly once, nontemporal.
        // read banks: (33*(2i+wu) + wj) % 32 -> 2-way, free.
        const int t0 = c * SC;
        #pragma unroll
        for (int p = 0; p < 4; ++p) {
            float* op = out + (size_t)p * plane + vehBase * T + t0;
            #pragma unroll
            for (int i = 0; i < V / 2; ++i) {
                const int vv = i * 2 + wu;
                __builtin_nontemporal_store(pool[(p * V + vv) * ST_PITCH + wj],
                                            &op[(size_t)vv * T + wj]);
            }
        }
        // no trailing fence needed: next iteration's control ds_writes alias
        // the pool, so neither compiler nor in-order DS unit reorders them
        // ahead of these reads.
    }
}

extern "C" void kernel_launch(void* const* d_in, const int* in_sizes, int n_in,
                              void* d_out, int out_size, void* d_ws, size_t ws_size,
                              hipStream_t stream) {
    const float* sx       = (const float*)d_in[0];
    const float* sy       = (const float*)d_in[1];
    const float* syaw     = (const float*)d_in[2];
    const float* ssp      = (const float*)d_in[3];
    const float* accel    = (const float*)d_in[4];
    const float* steering = (const float*)d_in[5];
    float* out = (float*)d_out;

    int B = in_sizes[0];
    dim3 block(V);
    dim3 grid(B / V);
    hipLaunchKernelGGL(bicycle_kernel, grid, block, 0, stream,
                       sx, sy, syaw, ssp, accel, steering, out, B);
}

// Round 3
// 503.355 us; speedup vs baseline: 1.0155x; 1.0155x over previous
//
#include <hip/hip_runtime.h>

#define T 256
#define TC 16            // chunk: 16 steps staged in LDS per round
#define NC (T / TC)      // 16 chunks
#define V 64             // one vehicle per thread, SINGLE-WAVE blocks
#define DT 0.05f
#define WHEELBASE 2.7f
#define MAX_STEER 0.5235987755982988f  // deg2rad(30)
#define MAX_SPEED 100.0f
#define FR 0.1f
#define FA 0.01f

// One thread per vehicle, one wave per block. Single 17 KB LDS buffer ->
// 9 blocks/CU (LDS-limited), i.e. 9 waves/CU vs round-2's 4. Blocks are
// independent (no s_barrier anywhere), so one block's store burst drains
// under another block's sim compute.
//
// Controls: per-thread row-major float4 loads (each thread's 4 loads/array
// hit ONE 128 B line -> L1 absorbs; proven non-bottleneck in rounds 0/1),
// prefetched one chunk ahead into ping-pong register sets A/B. No register
// copy and no LDS consumer -> the compiler's vmcnt wait for the prefetch
// covers only the 8 loads (+<=1 store), never a store-queue drain.
//
// LDS is written by the sim (per-lane rows), read back transposed for
// 64 B-contiguous coalesced stores. Single wave + in-order DS unit make
// this race-free without barriers; __builtin_amdgcn_wave_barrier() (emits
// no instruction) pins the compiler's scheduling order across the
// write->read->overwrite phases.
__global__ __launch_bounds__(V, 3) void bicycle_kernel(
    const float* __restrict__ sx, const float* __restrict__ sy,
    const float* __restrict__ syaw, const float* __restrict__ ssp,
    const float* __restrict__ accel, const float* __restrict__ steering,
    float* __restrict__ out, int B)
{
    // pad 17: sim write banks (17*tid + tt) % 32 -> 2-way (free);
    // writeout read banks ((4i+u)*17 + j) % 32 -> ~2-3-way (near-free).
    __shared__ float lds[4][V][TC + 1];   // 17,408 B -> 9 blocks/CU

    const int tid = threadIdx.x;
    const int b   = blockIdx.x * V + tid;

    float x   = sx[b];
    float y   = sy[b];
    float yaw = syaw[b];
    float sp  = ssp[b];

    const float4* a4 = (const float4*)(accel    + (size_t)b * T);
    const float4* s4 = (const float4*)(steering + (size_t)b * T);

    const size_t plane   = (size_t)B * T;
    const size_t vehBase = (size_t)blockIdx.x * V;

    const int u = tid >> 4;   // writeout: which of 4 vehicle rows per inst
    const int j = tid & 15;   // writeout: time offset within chunk

    float4 avA[TC / 4], svA[TC / 4], avB[TC / 4], svB[TC / 4];
    #pragma unroll
    for (int i = 0; i < TC / 4; ++i) { avA[i] = a4[i]; svA[i] = s4[i]; }

// One 16-step chunk: prefetch next chunk's controls into AVN/SVN, simulate
// 16 steps staging pre-step state to LDS, then transposed coalesced writeout.
#define CHUNK(C, AV, SV, AVN, SVN)                                         \
  {                                                                        \
    const int c_ = (C);                                                    \
    if (c_ + 1 < NC) {                                                     \
      _Pragma("unroll")                                                    \
      for (int i = 0; i < TC / 4; ++i) {                                   \
        AVN[i] = a4[(c_ + 1) * (TC / 4) + i];                              \
        SVN[i] = s4[(c_ + 1) * (TC / 4) + i];                              \
      }                                                                    \
    }                                                                      \
    _Pragma("unroll")                                                      \
    for (int k = 0; k < TC / 4; ++k) {                                     \
      const float acx[4] = {AV[k].x, AV[k].y, AV[k].z, AV[k].w};           \
      const float scx[4] = {SV[k].x, SV[k].y, SV[k].z, SV[k].w};           \
      _Pragma("unroll")                                                    \
      for (int m = 0; m < 4; ++m) {                                        \
        const int tt = k * 4 + m;                                          \
        lds[0][tid][tt] = x;                                               \
        lds[1][tid][tt] = y;                                               \
        lds[2][tid][tt] = yaw;                                             \
        lds[3][tid][tt] = sp;                                              \
        float fr    = fmaf(FA * sp, sp, sp * FR);                          \
        float spn   = fmaf(DT, acx[m] - fr, sp);                           \
        spn         = fminf(fmaxf(spn, 0.0f), MAX_SPEED);                  \
        float steer = fminf(fmaxf(scx[m], -MAX_STEER), MAX_STEER);         \
        float angv  = sp * __tanf(steer) * (1.0f / WHEELBASE);             \
        float s_, c2_;                                                     \
        __sincosf(yaw, &s_, &c2_);                                         \
        float spDT = sp * DT;                                              \
        x   = fmaf(spDT, c2_, x);                                          \
        y   = fmaf(spDT, s_, y);                                           \
        yaw = fmaf(angv, DT, yaw);                                         \
        sp  = spn;                                                         \
      }                                                                    \
    }                                                                      \
    __builtin_amdgcn_wave_barrier();  /* pin ds_write -> ds_read order */  \
    {                                                                      \
      const int t0 = c_ * TC;                                              \
      _Pragma("unroll")                                                    \
      for (int p = 0; p < 4; ++p) {                                        \
        float* op = out + (size_t)p * plane + vehBase * T + t0;            \
        _Pragma("unroll")                                                  \
        for (int i = 0; i < TC; ++i) {                                     \
          const int vv = i * 4 + u;                                        \
          op[(size_t)vv * T + j] = lds[p][vv][j];                          \
        }                                                                  \
      }                                                                    \
    }                                                                      \
    __builtin_amdgcn_wave_barrier();  /* pin ds_read -> next ds_write */   \
  }

    for (int c = 0; c < NC; c += 2) {
        CHUNK(c,     avA, svA, avB, svB)
        CHUNK(c + 1, avB, svB, avA, svA)
    }
#undef CHUNK
}

extern "C" void kernel_launch(void* const* d_in, const int* in_sizes, int n_in,
                              void* d_out, int out_size, void* d_ws, size_t ws_size,
                              hipStream_t stream) {
    const float* sx       = (const float*)d_in[0];
    const float* sy       = (const float*)d_in[1];
    const float* syaw     = (const float*)d_in[2];
    const float* ssp      = (const float*)d_in[3];
    const float* accel    = (const float*)d_in[4];
    const float* steering = (const float*)d_in[5];
    float* out = (float*)d_out;

    int B = in_sizes[0];
    dim3 block(V);
    dim3 grid(B / V);
    hipLaunchKernelGGL(bicycle_kernel, grid, block, 0, stream,
                       sx, sy, syaw, ssp, accel, steering, out, B);
}

// Round 5
// 385.001 us; speedup vs baseline: 1.3277x; 1.3074x over previous
//
#include <hip/hip_runtime.h>

#define T 256
#define SC 32            // super-chunk: 32 steps = one full 128 B line per row
#define NSC (T / SC)     // 8 super-chunks
#define V 64             // one vehicle per thread, SINGLE-WAVE blocks
#define DT 0.05f
#define WHEELBASE 2.7f
#define MAX_STEER 0.5235987755982988f  // deg2rad(30)
#define MAX_SPEED 100.0f
#define FR 0.1f
#define FA 0.01f
#define PITCH (SC + 1)   // 33: sim writes (tid+t)%32 2-way; readout 2-way

// Wave-local LDS fence: orders ds_write -> ds_read across lanes of ONE wave.
// No s_barrier, no vmcnt wait: global stores stay in flight and drain under
// the next super-chunk's compute.
__device__ __forceinline__ void lds_fence() {
    asm volatile("s_waitcnt lgkmcnt(0)" ::: "memory");
}

// Traffic-exact streaming: every 128 B line of accel/steering/out is touched
// by exactly one instruction of one wave, exactly once over the kernel.
//  - controls: 8 float4 = one full line per array per super-chunk, register
//    ping-pong (no LDS consumer -> no vmcnt alias pinning).
//  - out: 32 steps staged in LDS, then 32 consecutive lanes write one
//    vehicle-row's 128 B in ONE plain store inst (full line -> write-allocate
//    -> one clean eviction; no half-dirty evict/refetch like the TC=16 rounds).
__global__ __launch_bounds__(V) void bicycle_kernel(
    const float* __restrict__ sx, const float* __restrict__ sy,
    const float* __restrict__ syaw, const float* __restrict__ ssp,
    const float* __restrict__ accel, const float* __restrict__ steering,
    float* __restrict__ out, int B)
{
    __shared__ float pool[4][V][PITCH];   // 33,792 B

    const int tid = threadIdx.x;
    const int b   = blockIdx.x * V + tid;

    float x   = sx[b];
    float y   = sy[b];
    float yaw = syaw[b];
    float sp  = ssp[b];

    const float4* a4 = (const float4*)(accel    + (size_t)b * T);
    const float4* s4 = (const float4*)(steering + (size_t)b * T);

    const size_t plane   = (size_t)B * T;
    const size_t vehBase = (size_t)blockIdx.x * V;

    const int wu = tid >> 5;   // writeout: which vehicle of the pair
    const int wj = tid & 31;   // writeout: time offset within super-chunk

    // control ping-pong register sets (statically indexed -> stays in VGPRs)
    float4 avA[SC / 4], svA[SC / 4], avB[SC / 4], svB[SC / 4];
    #pragma unroll
    for (int i = 0; i < SC / 4; ++i) { avA[i] = a4[i]; svA[i] = s4[i]; }

// One super-chunk: prefetch next controls (full lines), simulate 32 steps
// staging pre-step state in LDS, fence, full-line transposed writeout.
#define SUPER(C, AV, SV, AVN, SVN)                                         \
  {                                                                        \
    const int c_ = (C);                                                    \
    if (c_ + 1 < NSC) {                                                    \
      _Pragma("unroll")                                                    \
      for (int i = 0; i < SC / 4; ++i) {                                   \
        AVN[i] = a4[(c_ + 1) * (SC / 4) + i];                              \
        SVN[i] = s4[(c_ + 1) * (SC / 4) + i];                              \
      }                                                                    \
    }                                                                      \
    _Pragma("unroll")                                                      \
    for (int k = 0; k < SC / 4; ++k) {                                     \
      const float acx[4] = {AV[k].x, AV[k].y, AV[k].z, AV[k].w};           \
      const float scx[4] = {SV[k].x, SV[k].y, SV[k].z, SV[k].w};           \
      _Pragma("unroll")                                                    \
      for (int m = 0; m < 4; ++m) {                                        \
        const int tt = k * 4 + m;                                          \
        pool[0][tid][tt] = x;                                              \
        pool[1][tid][tt] = y;                                              \
        pool[2][tid][tt] = yaw;                                            \
        pool[3][tid][tt] = sp;                                             \
        float fr    = fmaf(FA * sp, sp, sp * FR);                          \
        float spn   = fmaf(DT, acx[m] - fr, sp);                           \
        spn         = fminf(fmaxf(spn, 0.0f), MAX_SPEED);                  \
        float steer = fminf(fmaxf(scx[m], -MAX_STEER), MAX_STEER);         \
        float angv  = sp * __tanf(steer) * (1.0f / WHEELBASE);             \
        float s_, c2_;                                                     \
        __sincosf(yaw, &s_, &c2_);                                         \
        float spDT = sp * DT;                                              \
        x   = fmaf(spDT, c2_, x);                                          \
        y   = fmaf(spDT, s_, y);                                           \
        yaw = fmaf(angv, DT, yaw);                                         \
        sp  = spn;                                                         \
      }                                                                    \
    }                                                                      \
    lds_fence();  /* ds_writes visible wave-wide; stores NOT drained */    \
    {                                                                      \
      const int t0 = c_ * SC;                                              \
      _Pragma("unroll")                                                    \
      for (int p = 0; p < 4; ++p) {                                        \
        float* op = out + (size_t)p * plane + vehBase * T + t0;            \
        _Pragma("unroll")                                                  \
        for (int i = 0; i < V / 2; ++i) {                                  \
          const int vv = i * 2 + wu;                                       \
          op[(size_t)vv * T + wj] = pool[p][vv][wj];                       \
        }                                                                  \
      }                                                                    \
    }                                                                      \
    __builtin_amdgcn_wave_barrier();  /* pin reads before next ds_write */ \
  }

    for (int c = 0; c < NSC; c += 2) {
        SUPER(c,     avA, svA, avB, svB)
        SUPER(c + 1, avB, svB, avA, svA)
    }
#undef SUPER
}

extern "C" void kernel_launch(void* const* d_in, const int* in_sizes, int n_in,
                              void* d_out, int out_size, void* d_ws, size_t ws_size,
                              hipStream_t stream) {
    const float* sx       = (const float*)d_in[0];
    const float* sy       = (const float*)d_in[1];
    const float* syaw     = (const float*)d_in[2];
    const float* ssp      = (const float*)d_in[3];
    const float* accel    = (const float*)d_in[4];
    const float* steering = (const float*)d_in[5];
    float* out = (float*)d_out;

    int B = in_sizes[0];
    dim3 block(V);
    dim3 grid(B / V);
    hipLaunchKernelGGL(bicycle_kernel, grid, block, 0, stream,
                       sx, sy, syaw, ssp, accel, steering, out, B);
}